// Round 3
// baseline (187.777 us; speedup 1.0000x reference)
//
#include <hip/hip_runtime.h>

// Upsample2d (upfirdn2d, factor=2, down=1, k=[1,3,1] outer, gain*factor^2=4).
// Validated index algebra (rounds 1-2, absmax 3.1e-2):
//   out[n, c2, h2, w2] = sum_{u,v in 0..2} K[u][v] * T(ab=h2+u-2, bb=w2+v-2)
//   T nonzero iff ab,bb in [0,510] AND in odd 128-block ((x>>7)&1), then
//   T = x_n[(2*c2 + (ab>>8))*32768 + (ab&127)*256 + (bb>>8)*128 + (bb&127)]
//   K = [[1,3,1],[3,9,3],[1,3,1]] * 4/25.
//
// Round-3 change: 4-row blocking. One thread computes a 4(row)x4(col) output
// patch; the 6 tap rows ab=4g-2..4g+3 are each loaded ONCE (2 float4) and
// scatter-accumulated into the up-to-3 output rows that use them (output row
// r uses tap rows j=r..r+2, weight index u=j-r). Loads: 12 float4 / 16
// outputs vs 24 before; index math amortized 4x; FMAs factored via
// s_m = t_m + t_{m+2}. Zero row-groups (~half) skip all loads/FMAs via
// wave-uniform branches and just store zeros.

__global__ __launch_bounds__(256) void upfir2x_kernel(const float* __restrict__ x,
                                                      float* __restrict__ out) {
    const unsigned t  = blockIdx.x * 256u + threadIdx.x;
    const unsigned i  = t & 127u;           // column quad within row (w2 = 4i)
    const unsigned g  = (t >> 7) & 127u;    // row group: output rows h2 = 4g..4g+3
    const unsigned c2 = (t >> 14) & 127u;
    const unsigned n  = t >> 21;

    const float* __restrict__ xn = x + (size_t)n * 8388608u;

    // Column geometry (independent of row): taps bb = 4i-2 .. 4i+3 live in
    // 4-aligned quads BL=4i-4, BC=4i; validity is per-quad uniform.
    const int BL = (int)(i << 2) - 4;
    const int BC = (int)(i << 2);
    const bool vL = (BL >= 0) && (((BL >> 7) & 1) != 0);
    const bool vC = (((BC >> 7) & 1) != 0);
    const int offL = ((BL >> 8) << 7) + (BL & 127);   // (B>>8)*128 + (B&127)
    const int offC = ((BC >> 8) << 7) + (BC & 127);

    const float KE = 4.f / 25.f;    // corner
    const float KM = 12.f / 25.f;   // edge
    const float KC = 36.f / 25.f;   // center

    float acc[4][4] = {};           // [output row r][col j] — all indices static

    const int ab0 = (int)(g << 2) - 2;      // first tap row

#pragma unroll
    for (int j = 0; j < 6; ++j) {
        const int ab = ab0 + j;
        if ((unsigned)ab > 510u) continue;        // wave-uniform skip
        if (((ab >> 7) & 1) == 0) continue;       // even block -> zero-stuffed
        const float* __restrict__ base =
            xn + (((size_t)(2u * c2 + (unsigned)(ab >> 8))) << 15)
               + (size_t)((ab & 127) << 8);

        float4 xl = vL ? *reinterpret_cast<const float4*>(base + offL)
                       : make_float4(0.f, 0.f, 0.f, 0.f);
        float4 xc = vC ? *reinterpret_cast<const float4*>(base + offC)
                       : make_float4(0.f, 0.f, 0.f, 0.f);
        if (i == 127u) xc.w = 0.f;                // bb = 511 out of range

        const float t0 = xl.z, t1 = xl.w, t2 = xc.x,
                    t3 = xc.y, t4 = xc.z, t5 = xc.w;
        const float s0 = t0 + t2, s1 = t1 + t3, s2 = t2 + t4, s3 = t3 + t5;

#pragma unroll
        for (int u = 0; u < 3; ++u) {
            const int r = j - u;                  // output row in the group
            if (r < 0 || r > 3) continue;
            const float w0 = (u == 1) ? KM : KE;  // K[u][0] == K[u][2]
            const float w1 = (u == 1) ? KC : KM;  // K[u][1]
            acc[r][0] += w0 * s0 + w1 * t1;
            acc[r][1] += w0 * s1 + w1 * t2;
            acc[r][2] += w0 * s2 + w1 * t3;
            acc[r][3] += w0 * s3 + w1 * t4;
        }
    }

    // Stores: quad index ((n*128+c2)*512 + 4g + r)*128 + i, row stride 128.
    float4* __restrict__ oq = reinterpret_cast<float4*>(out)
        + ((((size_t)((n << 7) + c2) << 9) + (size_t)(g << 2)) << 7) + i;
#pragma unroll
    for (int r = 0; r < 4; ++r)
        oq[(size_t)r << 7] = make_float4(acc[r][0], acc[r][1], acc[r][2], acc[r][3]);
}

extern "C" void kernel_launch(void* const* d_in, const int* in_sizes, int n_in,
                              void* d_out, int out_size, void* d_ws, size_t ws_size,
                              hipStream_t stream) {
    const float* x   = (const float*)d_in[0];
    float*       out = (float*)d_out;
    // out_size = 134217728; 16 outputs per thread -> 8388608 threads
    const unsigned nthreads = (unsigned)(out_size / 16);
    dim3 grid(nthreads / 256u), block(256u);
    hipLaunchKernelGGL(upfir2x_kernel, grid, block, 0, stream, x, out);
}